// Round 2
// baseline (416.802 us; speedup 1.0000x reference)
//
#include <hip/hip_runtime.h>
#include <stdint.h>

typedef __attribute__((ext_vector_type(4))) int int4v;

#define M_DIM 8192
#define N_DIM 4096
#define K_DIM 4096

// ---------------- pack x: int32 -> int8, same layout ----------------
__global__ void pack_a_kernel(const int* __restrict__ x, uint32_t* __restrict__ a8,
                              int total4) {
    int idx = blockIdx.x * blockDim.x + threadIdx.x;
    if (idx < total4) {
        int4v v = ((const int4v*)x)[idx];
        uint32_t p = (uint32_t)(v.x & 0xff) | ((uint32_t)(v.y & 0xff) << 8) |
                     ((uint32_t)(v.z & 0xff) << 16) | ((uint32_t)(v.w & 0xff) << 24);
        a8[idx] = p;
    }
}

// ------------- transpose+pack weight: [K][N] int32 -> Bt[N][K] int8 -------------
__global__ void transpose_b_kernel(const int* __restrict__ w, int8_t* __restrict__ bt) {
    __shared__ int8_t tile[64 * 72];  // [n_local][k_local], rows padded to 72 B
    const int t = threadIdx.x;
    const int k0 = blockIdx.y * 64;
    const int n0 = blockIdx.x * 64;
#pragma unroll
    for (int it = 0; it < 4; ++it) {
        int li = t + it * 256;     // 0..1023
        int k = li >> 4;           // 0..63
        int c = li & 15;           // n-group of 4
        int4v g = *(const int4v*)&w[(size_t)(k0 + k) * N_DIM + n0 + c * 4];
        tile[(c * 4 + 0) * 72 + k] = (int8_t)g.x;
        tile[(c * 4 + 1) * 72 + k] = (int8_t)g.y;
        tile[(c * 4 + 2) * 72 + k] = (int8_t)g.z;
        tile[(c * 4 + 3) * 72 + k] = (int8_t)g.w;
    }
    __syncthreads();
#pragma unroll
    for (int it = 0; it < 4; ++it) {
        int li = t + it * 256;
        int n = li >> 4;           // 0..63
        int ck = li & 15;          // k-group of 4
        uint32_t p = *(const uint32_t*)&tile[n * 72 + ck * 4];
        *(uint32_t*)&bt[(size_t)(n0 + n) * K_DIM + k0 + ck * 4] = p;
    }
}

// ---------------- GEMM: m97 structure, i8 MFMA ----------------
__device__ inline void async16(const void* g, void* l) {
    __builtin_amdgcn_global_load_lds(
        (const __attribute__((address_space(1))) uint32_t*)g,
        (__attribute__((address_space(3))) uint32_t*)l, 16, 0, 0);
}

__global__ void __launch_bounds__(256)
gemm_kernel(const int8_t* __restrict__ A, const int8_t* __restrict__ Bt,
            const float* __restrict__ pa, const float* __restrict__ pb,
            int* __restrict__ out) {
    __shared__ int8_t smem[16384];
    int8_t* As = smem;          // [128][64] bytes
    int8_t* Bs = smem + 8192;   // [128][64] bytes

    const int t = threadIdx.x;
    const int lane = t & 63;
    const int wave = t >> 6;
    const int m0 = blockIdx.y * 128;
    const int n0 = blockIdx.x * 128;
    const int wm = (wave >> 1) * 64;
    const int wn = (wave & 1) * 64;
    const float scale = pa[0] * pb[0];

    int4v acc[4][4];
    int4v zero = {0, 0, 0, 0};
#pragma unroll
    for (int i = 0; i < 4; ++i)
#pragma unroll
        for (int j = 0; j < 4; ++j) acc[i][j] = zero;

    const int rA = lane >> 2;           // row within 16-row group
    const int cA = (lane & 3) * 16;     // byte offset within 64 B row
    const int koff = (lane >> 4) * 16;  // fragment k byte offset
    const int fr = lane & 15;           // fragment row

    for (int kt = 0; kt < K_DIM; kt += 64) {
        __syncthreads();
#pragma unroll
        for (int i = 0; i < 2; ++i) {
            int rb = wave * 16 + i * 64;  // wave-uniform base row
            async16(A + (size_t)(m0 + rb + rA) * K_DIM + kt + cA, As + rb * 64);
            async16(Bt + (size_t)(n0 + rb + rA) * K_DIM + kt + cA, Bs + rb * 64);
        }
        __syncthreads();

        int4v af[4], bf[4];
#pragma unroll
        for (int i = 0; i < 4; ++i) {
            af[i] = *(const int4v*)&As[(wm + i * 16 + fr) * 64 + koff];
            bf[i] = *(const int4v*)&Bs[(wn + i * 16 + fr) * 64 + koff];
        }
#pragma unroll
        for (int i = 0; i < 4; ++i)
#pragma unroll
            for (int j = 0; j < 4; ++j)
                acc[i][j] = __builtin_amdgcn_mfma_i32_16x16x64_i8(af[i], bf[j],
                                                                  acc[i][j], 0, 0, 0);
    }

    const int orow = (lane >> 4) * 4;
    const int ocol = lane & 15;
#pragma unroll
    for (int i = 0; i < 4; ++i)
#pragma unroll
        for (int j = 0; j < 4; ++j)
#pragma unroll
            for (int r = 0; r < 4; ++r) {
                float v = (float)acc[i][j][r] * scale;
                v = rintf(v);
                v = fminf(127.f, fmaxf(-128.f, v));
                out[(size_t)(m0 + wm + i * 16 + orow + r) * N_DIM +
                    (n0 + wn + j * 16 + ocol)] = (int)v;
            }
}

extern "C" void kernel_launch(void* const* d_in, const int* in_sizes, int n_in,
                              void* d_out, int out_size, void* d_ws, size_t ws_size,
                              hipStream_t stream) {
    const int* x = (const int*)d_in[0];
    const int* w = (const int*)d_in[1];
    const float* pa = (const float*)d_in[2];
    const float* pb = (const float*)d_in[3];
    int* out = (int*)d_out;

    int8_t* a8 = (int8_t*)d_ws;                       // 32 MiB
    int8_t* bt8 = a8 + (size_t)M_DIM * K_DIM;         // 16 MiB

    const int total4 = M_DIM * K_DIM / 4;
    pack_a_kernel<<<(total4 + 255) / 256, 256, 0, stream>>>(x, (uint32_t*)a8, total4);
    transpose_b_kernel<<<dim3(N_DIM / 64, K_DIM / 64), 256, 0, stream>>>(w, bt8);
    gemm_kernel<<<dim3(N_DIM / 128, M_DIM / 128), 256, 0, stream>>>(a8, bt8, pa, pb, out);
}